// Round 1
// baseline (493.066 us; speedup 1.0000x reference)
//
#include <hip/hip_runtime.h>
#include <cstddef>

#define NAGENT 8
#define DIN    128
#define HID    64
#define NACT   16

__device__ __forceinline__ float sigmoid_f(float v) {
    return 1.0f / (1.0f + __expf(-v));
}
__device__ __forceinline__ float tanh_f(float v) {
    v = fminf(fmaxf(v, -15.0f), 15.0f);
    float e = __expf(2.0f * v);
    return (e - 1.0f) / (e + 1.0f);
}

// acc[16] += sum_{k=0..63} lrow[k] * w[hh*wstride + k]   (w uniform per wave)
__device__ __forceinline__ void dot64(float acc[16], const float* __restrict__ lrow,
                                      const float* __restrict__ w, int wstride)
{
    #pragma unroll 1
    for (int k0 = 0; k0 < 64; k0 += 16) {
        float xk[16];
        #pragma unroll
        for (int kk = 0; kk < 16; ++kk) xk[kk] = lrow[k0 + kk];
        #pragma unroll
        for (int hh = 0; hh < 16; ++hh) {
            const float4* wp = (const float4*)(w + hh * wstride + k0);
            float4 w0 = wp[0], w1 = wp[1], w2 = wp[2], w3 = wp[3];
            float wv[16] = {w0.x, w0.y, w0.z, w0.w, w1.x, w1.y, w1.z, w1.w,
                            w2.x, w2.y, w2.z, w2.w, w3.x, w3.y, w3.z, w3.w};
            #pragma unroll
            for (int kk = 0; kk < 16; ++kk) acc[hh] = fmaf(xk[kk], wv[kk], acc[hh]);
        }
    }
}

extern "C" __global__ void __launch_bounds__(256)
rnn_agent_fused(const float* __restrict__ x,     // [B*A, D]
                const float* __restrict__ hin,   // [B, A, H]
                const float* __restrict__ W1,    // [A, H, D]
                const float* __restrict__ b1,    // [A, H]
                const float* __restrict__ Wih,   // [A, 3H, H]
                const float* __restrict__ bih,   // [A, 3H]
                const float* __restrict__ Whh,   // [A, 3H, H]
                const float* __restrict__ bhh,   // [A, 3H]
                const float* __restrict__ W2,    // [A, NACT, H]
                const float* __restrict__ b2,    // [A, NACT]
                float* __restrict__ qout,        // [B*A, NACT]
                float* __restrict__ hout,        // [B, A, H]
                int B)
{
    const int a    = blockIdx.y;
    const int b0   = blockIdx.x * 64;
    const int t    = threadIdx.x;
    const int row  = t & 63;
    const int quad = t >> 6;
    const int h0   = quad * 16;

    __shared__ float xs [64 * 65];  // x chunk [64 rows][64 cols], pad stride 65; reused for h_new
    __shared__ float hsm[64 * 65];  // hidden tile
    __shared__ float zs [64 * 65];  // z1 tile

    // stage hidden tile (coalesced: consecutive t -> consecutive cols)
    #pragma unroll
    for (int i = 0; i < 16; ++i) {
        int idx = t + i * 256;
        int r = idx >> 6, c = idx & 63;
        hsm[r * 65 + c] = hin[((size_t)(b0 + r) * NAGENT + a) * HID + c];
    }

    // ---------------- fc1: z1 = relu(x @ W1^T + b1) ----------------
    float acc[16];
    #pragma unroll
    for (int i = 0; i < 16; ++i) acc[i] = b1[a * HID + h0 + i];

    const float* W1a = W1 + (size_t)a * HID * DIN;
    #pragma unroll 1
    for (int dc = 0; dc < DIN; dc += 64) {
        __syncthreads();  // protect xs (hsm writes on iter0 also ordered before later reads)
        #pragma unroll
        for (int i = 0; i < 16; ++i) {
            int idx = t + i * 256;
            int r = idx >> 6, c = idx & 63;
            xs[r * 65 + c] = x[((size_t)(b0 + r) * NAGENT + a) * DIN + dc + c];
        }
        __syncthreads();
        dot64(acc, xs + row * 65, W1a + h0 * DIN + dc, DIN);
    }

    #pragma unroll
    for (int i = 0; i < 16; ++i) zs[row * 65 + h0 + i] = fmaxf(acc[i], 0.0f);
    __syncthreads();

    // ---------------- GRU gates ----------------
    const float* Wia  = Wih + (size_t)a * 3 * HID * HID;
    const float* Wha  = Whh + (size_t)a * 3 * HID * HID;
    const float* zrow = zs  + row * 65;
    const float* hrow = hsm + row * 65;

    float accB[16], rg[16], zgg[16], hnew[16];

    // r gate (g offset 0)
    #pragma unroll
    for (int i = 0; i < 16; ++i) acc[i]  = bih[a * 3 * HID + 0 * HID + h0 + i];
    #pragma unroll
    for (int i = 0; i < 16; ++i) accB[i] = bhh[a * 3 * HID + 0 * HID + h0 + i];
    dot64(acc,  zrow, Wia + (0 * HID + h0) * HID, HID);
    dot64(accB, hrow, Wha + (0 * HID + h0) * HID, HID);
    #pragma unroll
    for (int i = 0; i < 16; ++i) rg[i] = sigmoid_f(acc[i] + accB[i]);

    // z gate (g offset H)
    #pragma unroll
    for (int i = 0; i < 16; ++i) acc[i]  = bih[a * 3 * HID + 1 * HID + h0 + i];
    #pragma unroll
    for (int i = 0; i < 16; ++i) accB[i] = bhh[a * 3 * HID + 1 * HID + h0 + i];
    dot64(acc,  zrow, Wia + (1 * HID + h0) * HID, HID);
    dot64(accB, hrow, Wha + (1 * HID + h0) * HID, HID);
    #pragma unroll
    for (int i = 0; i < 16; ++i) zgg[i] = sigmoid_f(acc[i] + accB[i]);

    // n gate (g offset 2H)
    #pragma unroll
    for (int i = 0; i < 16; ++i) acc[i]  = bih[a * 3 * HID + 2 * HID + h0 + i];
    #pragma unroll
    for (int i = 0; i < 16; ++i) accB[i] = bhh[a * 3 * HID + 2 * HID + h0 + i];
    dot64(acc,  zrow, Wia + (2 * HID + h0) * HID, HID);
    dot64(accB, hrow, Wha + (2 * HID + h0) * HID, HID);
    #pragma unroll
    for (int i = 0; i < 16; ++i) {
        float n = tanh_f(acc[i] + rg[i] * accB[i]);
        float hprev = hrow[h0 + i];
        hnew[i] = (1.0f - zgg[i]) * n + zgg[i] * hprev;
    }

    // store h_new: global (contiguous 64B per lane) + LDS (reuse xs)
    {
        float* hp = hout + ((size_t)(b0 + row) * NAGENT + a) * HID + h0;
        #pragma unroll
        for (int i = 0; i < 4; ++i) {
            *((float4*)(hp + 4 * i)) =
                make_float4(hnew[4*i], hnew[4*i+1], hnew[4*i+2], hnew[4*i+3]);
        }
        #pragma unroll
        for (int i = 0; i < 16; ++i) xs[row * 65 + h0 + i] = hnew[i];
    }
    __syncthreads();

    // ---------------- fc2: q = h_new @ W2^T + b2 ----------------
    // remap: thread owns (row, actions nq*4 .. nq*4+3)
    const int nq = quad;
    const float* W2a = W2 + (size_t)a * NACT * HID;
    const float* hr2 = xs + row * 65;
    float q[4];
    #pragma unroll
    for (int j = 0; j < 4; ++j) q[j] = b2[a * NACT + nq * 4 + j];

    #pragma unroll 1
    for (int k0 = 0; k0 < 64; k0 += 16) {
        float xk[16];
        #pragma unroll
        for (int kk = 0; kk < 16; ++kk) xk[kk] = hr2[k0 + kk];
        #pragma unroll
        for (int j = 0; j < 4; ++j) {
            const float4* wp = (const float4*)(W2a + (nq * 4 + j) * HID + k0);
            float4 w0 = wp[0], w1 = wp[1], w2 = wp[2], w3 = wp[3];
            float wv[16] = {w0.x, w0.y, w0.z, w0.w, w1.x, w1.y, w1.z, w1.w,
                            w2.x, w2.y, w2.z, w2.w, w3.x, w3.y, w3.z, w3.w};
            #pragma unroll
            for (int kk = 0; kk < 16; ++kk) q[j] = fmaf(xk[kk], wv[kk], q[j]);
        }
    }

    float* qp = qout + ((size_t)(b0 + row) * NAGENT + a) * NACT + nq * 4;
    *((float4*)qp) = make_float4(q[0], q[1], q[2], q[3]);
}

extern "C" void kernel_launch(void* const* d_in, const int* in_sizes, int n_in,
                              void* d_out, int out_size, void* d_ws, size_t ws_size,
                              hipStream_t stream)
{
    const float* x   = (const float*)d_in[0];
    const float* hin = (const float*)d_in[1];
    const float* W1  = (const float*)d_in[2];
    const float* b1  = (const float*)d_in[3];
    const float* Wih = (const float*)d_in[4];
    const float* bih = (const float*)d_in[5];
    const float* Whh = (const float*)d_in[6];
    const float* bhh = (const float*)d_in[7];
    const float* W2  = (const float*)d_in[8];
    const float* b2  = (const float*)d_in[9];

    const int B = in_sizes[0] / (NAGENT * DIN);   // 16384

    float* qout = (float*)d_out;                              // [B*A, NACT]
    float* hout = (float*)d_out + (size_t)B * NAGENT * NACT;  // [B, A, H]

    dim3 grid(B / 64, NAGENT);
    rnn_agent_fused<<<grid, 256, 0, stream>>>(x, hin, W1, b1, Wih, bih, Whh, bhh,
                                              W2, b2, qout, hout, B);
}

// Round 2
// 87.375 us; speedup vs baseline: 5.6431x; 5.6431x over previous
//
#include <hip/hip_runtime.h>
#include <cstddef>

#define NAGENT 8
#define DIN    128
#define HID    64
#define NACT   16

typedef __attribute__((ext_vector_type(8))) short bf16x8;
typedef __attribute__((ext_vector_type(4))) float f32x4;

__device__ __forceinline__ short f2bf(float f) {
    union { float f; unsigned u; } v; v.f = f;
    unsigned r = v.u + 0x7FFFu + ((v.u >> 16) & 1u);   // RNE (finite data)
    return (short)(r >> 16);
}
__device__ __forceinline__ float sigmoid_f(float v) { return 1.0f / (1.0f + __expf(-v)); }
__device__ __forceinline__ float tanh_f(float v) {
    v = fminf(fmaxf(v, -15.0f), 15.0f);
    float e = __expf(2.0f * v);
    return (e - 1.0f) / (e + 1.0f);
}
// load 8 consecutive fp32 -> bf16x8 A-fragment chunk
__device__ __forceinline__ bf16x8 cvt8(const float* __restrict__ p) {
    float4 v0 = ((const float4*)p)[0];
    float4 v1 = ((const float4*)p)[1];
    bf16x8 r;
    r[0] = f2bf(v0.x); r[1] = f2bf(v0.y); r[2] = f2bf(v0.z); r[3] = f2bf(v0.w);
    r[4] = f2bf(v1.x); r[5] = f2bf(v1.y); r[6] = f2bf(v1.z); r[7] = f2bf(v1.w);
    return r;
}

// ---- weight fp32 -> bf16 conversion into d_ws ----
// layout (shorts): W1b[8*64*128]=65536 | Wihb[8*192*64]=98304 | Whhb[98304] | W2b[8*16*64]=8192
extern "C" __global__ void __launch_bounds__(256)
conv_weights(const float* __restrict__ W1, const float* __restrict__ Wih,
             const float* __restrict__ Whh, const float* __restrict__ W2,
             short* __restrict__ ws)
{
    int i = (blockIdx.x * 256 + threadIdx.x) * 4;   // 270336 elems total, grid covers exactly
    const float* s; int local;
    if (i < 65536)       { s = W1;  local = i; }
    else if (i < 163840) { s = Wih; local = i - 65536; }
    else if (i < 262144) { s = Whh; local = i - 163840; }
    else                 { s = W2;  local = i - 262144; }
    float4 v = *(const float4*)(s + local);
    short4 o; o.x = f2bf(v.x); o.y = f2bf(v.y); o.z = f2bf(v.z); o.w = f2bf(v.w);
    *(short4*)(ws + i) = o;
}

// ---- fused agent kernel: 4 independent waves, 16 rows each, no barriers ----
extern "C" __global__ void __launch_bounds__(256)
rnn_agent_mfma(const float* __restrict__ x,     // [B*A, D]
               const float* __restrict__ hin,   // [B, A, H]
               const float* __restrict__ b1,    // [A, H]
               const float* __restrict__ bih,   // [A, 3H]
               const float* __restrict__ bhh,   // [A, 3H]
               const float* __restrict__ b2,    // [A, NACT]
               const short* __restrict__ W1b,   // [A,64,128] bf16
               const short* __restrict__ Wihb,  // [A,192,64] bf16
               const short* __restrict__ Whhb,  // [A,192,64] bf16
               const short* __restrict__ W2b,   // [A,16,64]  bf16
               float* __restrict__ qout,        // [B*A, NACT]
               float* __restrict__ hout)        // [B, A, H]
{
    const int a    = blockIdx.y;
    const int t    = threadIdx.x;
    const int lane = t & 63;
    const int wid  = t >> 6;
    const int lr   = lane & 15;       // A-row / B-col / D-col within 16
    const int lk   = lane >> 4;       // k-subchunk 0..3
    const int rbase = blockIdx.x * 64 + wid * 16;   // batch-row base of this wave
    const int arow  = rbase + lr;                   // this lane's A-fragment row

    // per-wave transpose buffer [16 rows][64 cols] bf16, stride 128B, XOR-swizzled
    __shared__ short zs[4 * 16 * 64];
    char* zb = (char*)(zs + wid * 16 * 64);

    // ---------------- fc1: z1 = relu(x @ W1^T + b1) ----------------
    f32x4 acc1[4];
    #pragma unroll
    for (int n = 0; n < 4; ++n) {
        float bv = b1[a * HID + n * 16 + lr];
        acc1[n] = (f32x4){bv, bv, bv, bv};
    }
    const short* W1a = W1b + a * HID * DIN;
    const float* xrow = x + ((size_t)arow * NAGENT + a) * DIN;
    #pragma unroll
    for (int k = 0; k < 4; ++k) {                      // K = 128 = 4 x 32
        bf16x8 xa = cvt8(xrow + k * 32 + lk * 8);
        #pragma unroll
        for (int n = 0; n < 4; ++n) {
            bf16x8 wb = *(const bf16x8*)(W1a + (n * 16 + lr) * DIN + k * 32 + lk * 8);
            acc1[n] = __builtin_amdgcn_mfma_f32_16x16x32_bf16(xa, wb, acc1[n], 0, 0, 0);
        }
    }
    // write z1 (D-layout: row = lk*4+j, col = n*16+lr) to swizzled LDS
    #pragma unroll
    for (int n = 0; n < 4; ++n) {
        #pragma unroll
        for (int j = 0; j < 4; ++j) {
            int row = lk * 4 + j, col = n * 16 + lr;
            float v = fmaxf(acc1[n][j], 0.0f);
            *(short*)(zb + row * 128 + (((col * 2)) ^ ((row & 7) << 4))) = f2bf(v);
        }
    }

    // ---------------- GRU gates ----------------
    const short* Wia = Wihb + a * 3 * HID * HID;
    const short* Wha = Whhb + a * 3 * HID * HID;
    const float* hrow = hin + ((size_t)arow * NAGENT + a) * HID;
    float rg[16], zg[16];
    f32x4 aI[4], aH[4];

    #pragma unroll
    for (int g = 0; g < 3; ++g) {
        #pragma unroll
        for (int n = 0; n < 4; ++n) {
            float bi = bih[a * 3 * HID + g * HID + n * 16 + lr];
            float bh = bhh[a * 3 * HID + g * HID + n * 16 + lr];
            aI[n] = (f32x4){bi, bi, bi, bi};
            aH[n] = (f32x4){bh, bh, bh, bh};
        }
        #pragma unroll
        for (int kk = 0; kk < 2; ++kk) {               // K = 64 = 2 x 32
            bf16x8 za = *(const bf16x8*)(zb + lr * 128 + ((kk * 64 + lk * 16) ^ ((lr & 7) << 4)));
            bf16x8 ha = cvt8(hrow + kk * 32 + lk * 8);
            #pragma unroll
            for (int n = 0; n < 4; ++n) {
                bf16x8 wi = *(const bf16x8*)(Wia + (g * HID + n * 16 + lr) * HID + kk * 32 + lk * 8);
                bf16x8 wh = *(const bf16x8*)(Wha + (g * HID + n * 16 + lr) * HID + kk * 32 + lk * 8);
                aI[n] = __builtin_amdgcn_mfma_f32_16x16x32_bf16(za, wi, aI[n], 0, 0, 0);
                aH[n] = __builtin_amdgcn_mfma_f32_16x16x32_bf16(ha, wh, aH[n], 0, 0, 0);
            }
        }
        if (g == 0) {
            #pragma unroll
            for (int n = 0; n < 4; ++n)
                #pragma unroll
                for (int j = 0; j < 4; ++j) rg[n * 4 + j] = sigmoid_f(aI[n][j] + aH[n][j]);
        } else if (g == 1) {
            #pragma unroll
            for (int n = 0; n < 4; ++n)
                #pragma unroll
                for (int j = 0; j < 4; ++j) zg[n * 4 + j] = sigmoid_f(aI[n][j] + aH[n][j]);
        } else {
            // n gate + GRU elementwise + h_new store (global fp32 + swizzled LDS bf16)
            #pragma unroll
            for (int n = 0; n < 4; ++n) {
                #pragma unroll
                for (int j = 0; j < 4; ++j) {
                    int row = lk * 4 + j, col = n * 16 + lr;
                    float nn = tanh_f(aI[n][j] + rg[n * 4 + j] * aH[n][j]);
                    float hp = hin[((size_t)(rbase + row) * NAGENT + a) * HID + col];
                    float zv = zg[n * 4 + j];
                    float hv = (1.0f - zv) * nn + zv * hp;
                    hout[((size_t)(rbase + row) * NAGENT + a) * HID + col] = hv;
                    *(short*)(zb + row * 128 + (((col * 2)) ^ ((row & 7) << 4))) = f2bf(hv);
                }
            }
        }
    }

    // ---------------- fc2: q = h_new @ W2^T + b2 ----------------
    f32x4 q;
    { float bq = b2[a * NACT + lr]; q = (f32x4){bq, bq, bq, bq}; }
    const short* W2a = W2b + a * NACT * HID;
    #pragma unroll
    for (int kk = 0; kk < 2; ++kk) {
        bf16x8 ha = *(const bf16x8*)(zb + lr * 128 + ((kk * 64 + lk * 16) ^ ((lr & 7) << 4)));
        bf16x8 wb = *(const bf16x8*)(W2a + lr * HID + kk * 32 + lk * 8);
        q = __builtin_amdgcn_mfma_f32_16x16x32_bf16(ha, wb, q, 0, 0, 0);
    }
    #pragma unroll
    for (int j = 0; j < 4; ++j) {
        int row = lk * 4 + j;
        qout[((size_t)(rbase + row) * NAGENT + a) * NACT + lr] = q[j];
    }
}

extern "C" void kernel_launch(void* const* d_in, const int* in_sizes, int n_in,
                              void* d_out, int out_size, void* d_ws, size_t ws_size,
                              hipStream_t stream)
{
    const float* x   = (const float*)d_in[0];
    const float* hin = (const float*)d_in[1];
    const float* W1  = (const float*)d_in[2];
    const float* b1  = (const float*)d_in[3];
    const float* Wih = (const float*)d_in[4];
    const float* bih = (const float*)d_in[5];
    const float* Whh = (const float*)d_in[6];
    const float* bhh = (const float*)d_in[7];
    const float* W2  = (const float*)d_in[8];
    const float* b2  = (const float*)d_in[9];

    const int B = in_sizes[0] / (NAGENT * DIN);   // 16384

    float* qout = (float*)d_out;                              // [B*A, NACT]
    float* hout = (float*)d_out + (size_t)B * NAGENT * NACT;  // [B, A, H]

    short* W1b  = (short*)d_ws;                // 65536
    short* Wihb = W1b  + 65536;                // 98304
    short* Whhb = Wihb + 98304;                // 98304
    short* W2b  = Whhb + 98304;                // 8192   (total 540,672 B in d_ws)

    conv_weights<<<264, 256, 0, stream>>>(W1, Wih, Whh, W2, W1b);

    dim3 grid(B / 64, NAGENT);
    rnn_agent_mfma<<<grid, 256, 0, stream>>>(x, hin, b1, bih, bhh, b2,
                                             W1b, Wihb, Whhb, W2b, qout, hout);
}

// Round 3
// 54.829 us; speedup vs baseline: 8.9928x; 1.5936x over previous
//
#include <hip/hip_runtime.h>
#include <cstddef>

#define NAGENT 8
#define DIN    128
#define HID    64
#define NACT   16

typedef __attribute__((ext_vector_type(8))) short bf16x8;
typedef __attribute__((ext_vector_type(4))) float f32x4;

__device__ __forceinline__ short f2bf(float f) {
    union { float f; unsigned u; } v; v.f = f;
    unsigned r = v.u + 0x7FFFu + ((v.u >> 16) & 1u);   // RNE (finite data)
    return (short)(r >> 16);
}
__device__ __forceinline__ float sigmoid_f(float v) { return 1.0f / (1.0f + __expf(-v)); }
__device__ __forceinline__ float tanh_f(float v) {
    v = fminf(fmaxf(v, -15.0f), 15.0f);
    float e = __expf(2.0f * v);
    return (e - 1.0f) / (e + 1.0f);
}
__device__ __forceinline__ bf16x8 cvt8pair(float4 v0, float4 v1) {
    bf16x8 r;
    r[0] = f2bf(v0.x); r[1] = f2bf(v0.y); r[2] = f2bf(v0.z); r[3] = f2bf(v0.w);
    r[4] = f2bf(v1.x); r[5] = f2bf(v1.y); r[6] = f2bf(v1.z); r[7] = f2bf(v1.w);
    return r;
}
__device__ __forceinline__ void gload_lds16(const void* g, void* l) {
    __builtin_amdgcn_global_load_lds(
        (const __attribute__((address_space(1))) unsigned int*)g,
        (__attribute__((address_space(3))) unsigned int*)l, 16, 0, 0);
}

// ---------------- weight fp32 -> bf16 fragment-major packing ----------------
// Per-agent packed layout (shorts), base a*33792:
//   W1  chunks c in [0,1024):    c = (n*4+k)*64 + lane      -> W1[a][n*16+lr][k*32+lk*8 ..+8]
//   Wih chunks c in [1024,2560): c-1024 = ((g*4+n)*2+kk)*64+lane -> Wih[a][g*64+n*16+lr][kk*32+lk*8..]
//   Whh chunks c in [2560,4096): same with Whh
//   W2  chunks c in [4096,4224): c-4096 = kk*64+lane        -> W2[a][lr][kk*32+lk*8..]
// dst chunk index == c in all sections (sections contiguous, equal ordering).
extern "C" __global__ void __launch_bounds__(256)
conv_weights_packed(const float* __restrict__ W1, const float* __restrict__ Wih,
                    const float* __restrict__ Whh, const float* __restrict__ W2,
                    short* __restrict__ ws)
{
    const int a = blockIdx.y;
    const int c = blockIdx.x * 256 + threadIdx.x;
    if (c >= 4224) return;
    const int lane = c & 63, lr = lane & 15, lk = lane >> 4;
    const float* src;
    if (c < 1024) {
        int n = c >> 8, k = (c >> 6) & 3;
        src = W1 + a * 8192 + (n * 16 + lr) * 128 + k * 32 + lk * 8;
    } else if (c < 2560) {
        int idx = (c - 1024) >> 6;
        int g = idx >> 3, n = (idx >> 1) & 3, kk = idx & 1;
        src = Wih + a * 12288 + (g * 64 + n * 16 + lr) * 64 + kk * 32 + lk * 8;
    } else if (c < 4096) {
        int idx = (c - 2560) >> 6;
        int g = idx >> 3, n = (idx >> 1) & 3, kk = idx & 1;
        src = Whh + a * 12288 + (g * 64 + n * 16 + lr) * 64 + kk * 32 + lk * 8;
    } else {
        int kk = (c - 4096) >> 6;
        src = W2 + a * 1024 + lr * 64 + kk * 32 + lk * 8;
    }
    float4 v0 = ((const float4*)src)[0];
    float4 v1 = ((const float4*)src)[1];
    bf16x8 o = cvt8pair(v0, v1);
    *(bf16x8*)(ws + (size_t)a * 33792 + (size_t)c * 8) = o;
}

// ---------------- main fused kernel ----------------
// grid (B/256, A), 256 threads (4 waves). Block: stage agent weights (66KB) to
// LDS once; each wave processes 4 row-tiles of 16 with 1-tile-ahead x/h prefetch.
extern "C" __global__ void __launch_bounds__(256, 2)
rnn_main(const float* __restrict__ x,     // [B*A, D]
         const float* __restrict__ hin,   // [B, A, H]
         const float* __restrict__ b1, const float* __restrict__ bih,
         const float* __restrict__ bhh, const float* __restrict__ b2,
         const short* __restrict__ wsp,   // packed bf16 weights
         float* __restrict__ qout,        // [B*A, NACT]
         float* __restrict__ hout)        // [B, A, H]
{
    const int a    = blockIdx.y;
    const int bx   = blockIdx.x;
    const int t    = threadIdx.x;
    const int wid  = t >> 6;
    const int lane = t & 63;
    const int lr   = lane & 15;
    const int lk   = lane >> 4;

    __shared__ short wlds[33792];         // 66 KB packed weights
    __shared__ short zs[4 * 16 * 64];     // per-wave 2KB transpose buffer
    char* zb = (char*)(zs + wid * 16 * 64);

    // ---- stage weights: 66 rounds x 1KB, split across 4 waves ----
    const short* wsA = wsp + (size_t)a * 33792;
    for (int r = wid; r < 66; r += 4)
        gload_lds16(wsA + (size_t)r * 512 + lane * 8, wlds + r * 512);

    // ---- hoist biases (tile-invariant, per-lane) ----
    float b1v[4], biv[12], bhv[12];
    #pragma unroll
    for (int n = 0; n < 4; ++n) b1v[n] = b1[a * HID + n * 16 + lr];
    #pragma unroll
    for (int g = 0; g < 3; ++g)
        #pragma unroll
        for (int n = 0; n < 4; ++n) {
            biv[g * 4 + n] = bih[a * 3 * HID + g * HID + n * 16 + lr];
            bhv[g * 4 + n] = bhh[a * 3 * HID + g * HID + n * 16 + lr];
        }
    float bqv = b2[a * NACT + lr];

    __syncthreads();   // weights staged (drains vmcnt)

    const int tile0 = bx * 16 + wid * 4;

    float4 curx[8], curh[4], nxtx[8], nxth[4];

    auto load_tile = [&](int tile, float4* xr, float4* hr) {
        const int arow = tile * 16 + lr;
        const float* xrow = x + ((size_t)arow * NAGENT + a) * DIN + lk * 8;
        const float* hrow = hin + ((size_t)arow * NAGENT + a) * HID + lk * 8;
        #pragma unroll
        for (int k = 0; k < 4; ++k) {
            xr[2 * k]     = *(const float4*)(xrow + k * 32);
            xr[2 * k + 1] = *(const float4*)(xrow + k * 32 + 4);
        }
        #pragma unroll
        for (int kk = 0; kk < 2; ++kk) {
            hr[2 * kk]     = *(const float4*)(hrow + kk * 32);
            hr[2 * kk + 1] = *(const float4*)(hrow + kk * 32 + 4);
        }
    };

    auto compute = [&](int tile, const float4* xr, const float4* hr) {
        bf16x8 xf[4], hf[2];
        #pragma unroll
        for (int k = 0; k < 4; ++k) xf[k] = cvt8pair(xr[2 * k], xr[2 * k + 1]);
        #pragma unroll
        for (int kk = 0; kk < 2; ++kk) hf[kk] = cvt8pair(hr[2 * kk], hr[2 * kk + 1]);

        // ---- fc1 ----
        f32x4 acc1[4];
        #pragma unroll
        for (int n = 0; n < 4; ++n) acc1[n] = (f32x4){b1v[n], b1v[n], b1v[n], b1v[n]};
        #pragma unroll
        for (int k = 0; k < 4; ++k)
            #pragma unroll
            for (int n = 0; n < 4; ++n) {
                bf16x8 wb = *(const bf16x8*)(wlds + ((n * 4 + k) * 64 + lane) * 8);
                acc1[n] = __builtin_amdgcn_mfma_f32_16x16x32_bf16(xf[k], wb, acc1[n], 0, 0, 0);
            }
        #pragma unroll
        for (int n = 0; n < 4; ++n)
            #pragma unroll
            for (int j = 0; j < 4; ++j) {
                int row = lk * 4 + j, col = n * 16 + lr;
                *(short*)(zb + row * 128 + ((col * 2) ^ ((row & 7) << 4))) =
                    f2bf(fmaxf(acc1[n][j], 0.0f));
            }

        // ---- GRU gates ----
        float rg[16], zg[16];
        #pragma unroll
        for (int g = 0; g < 3; ++g) {
            f32x4 aI[4], aH[4];
            #pragma unroll
            for (int n = 0; n < 4; ++n) {
                float bi = biv[g * 4 + n], bh = bhv[g * 4 + n];
                aI[n] = (f32x4){bi, bi, bi, bi};
                aH[n] = (f32x4){bh, bh, bh, bh};
            }
            #pragma unroll
            for (int kk = 0; kk < 2; ++kk) {
                bf16x8 za = *(const bf16x8*)(zb + lr * 128 +
                                             ((kk * 64 + lk * 16) ^ ((lr & 7) << 4)));
                #pragma unroll
                for (int n = 0; n < 4; ++n) {
                    bf16x8 wi = *(const bf16x8*)(wlds + 8192 +
                                  (((g * 4 + n) * 2 + kk) * 64 + lane) * 8);
                    bf16x8 wh = *(const bf16x8*)(wlds + 20480 +
                                  (((g * 4 + n) * 2 + kk) * 64 + lane) * 8);
                    aI[n] = __builtin_amdgcn_mfma_f32_16x16x32_bf16(za, wi, aI[n], 0, 0, 0);
                    aH[n] = __builtin_amdgcn_mfma_f32_16x16x32_bf16(hf[kk], wh, aH[n], 0, 0, 0);
                }
            }
            if (g == 0) {
                #pragma unroll
                for (int n = 0; n < 4; ++n)
                    #pragma unroll
                    for (int j = 0; j < 4; ++j)
                        rg[n * 4 + j] = sigmoid_f(aI[n][j] + aH[n][j]);
            } else if (g == 1) {
                #pragma unroll
                for (int n = 0; n < 4; ++n)
                    #pragma unroll
                    for (int j = 0; j < 4; ++j)
                        zg[n * 4 + j] = sigmoid_f(aI[n][j] + aH[n][j]);
            } else {
                #pragma unroll
                for (int n = 0; n < 4; ++n)
                    #pragma unroll
                    for (int j = 0; j < 4; ++j) {
                        int row = lk * 4 + j, col = n * 16 + lr;
                        float nn = tanh_f(aI[n][j] + rg[n * 4 + j] * aH[n][j]);
                        float hp = hin[((size_t)(tile * 16 + row) * NAGENT + a) * HID + col];
                        float zv = zg[n * 4 + j];
                        float hv = (1.0f - zv) * nn + zv * hp;
                        hout[((size_t)(tile * 16 + row) * NAGENT + a) * HID + col] = hv;
                        *(short*)(zb + row * 128 + ((col * 2) ^ ((row & 7) << 4))) = f2bf(hv);
                    }
            }
        }

        // ---- fc2 ----
        f32x4 q = (f32x4){bqv, bqv, bqv, bqv};
        #pragma unroll
        for (int kk = 0; kk < 2; ++kk) {
            bf16x8 ha = *(const bf16x8*)(zb + lr * 128 +
                                         ((kk * 64 + lk * 16) ^ ((lr & 7) << 4)));
            bf16x8 wb = *(const bf16x8*)(wlds + 32768 + (kk * 64 + lane) * 8);
            q = __builtin_amdgcn_mfma_f32_16x16x32_bf16(ha, wb, q, 0, 0, 0);
        }
        #pragma unroll
        for (int j = 0; j < 4; ++j)
            qout[((size_t)(tile * 16 + lk * 4 + j) * NAGENT + a) * NACT + lr] = q[j];
    };

    // ---- pipelined tile loop: prefetch next tile during compute ----
    load_tile(tile0, curx, curh);
    #pragma unroll
    for (int i = 0; i < 4; ++i) {
        if (i < 3) load_tile(tile0 + i + 1, nxtx, nxth);
        compute(tile0 + i, curx, curh);
        if (i < 3) {
            #pragma unroll
            for (int u = 0; u < 8; ++u) curx[u] = nxtx[u];
            #pragma unroll
            for (int u = 0; u < 4; ++u) curh[u] = nxth[u];
        }
    }
}

extern "C" void kernel_launch(void* const* d_in, const int* in_sizes, int n_in,
                              void* d_out, int out_size, void* d_ws, size_t ws_size,
                              hipStream_t stream)
{
    const float* x   = (const float*)d_in[0];
    const float* hin = (const float*)d_in[1];
    const float* W1  = (const float*)d_in[2];
    const float* b1  = (const float*)d_in[3];
    const float* Wih = (const float*)d_in[4];
    const float* bih = (const float*)d_in[5];
    const float* Whh = (const float*)d_in[6];
    const float* bhh = (const float*)d_in[7];
    const float* W2  = (const float*)d_in[8];
    const float* b2  = (const float*)d_in[9];

    const int B = in_sizes[0] / (NAGENT * DIN);   // 16384

    float* qout = (float*)d_out;                              // [B*A, NACT]
    float* hout = (float*)d_out + (size_t)B * NAGENT * NACT;  // [B, A, H]

    short* wsp = (short*)d_ws;                                // 540,672 B packed

    conv_weights_packed<<<dim3(17, NAGENT), 256, 0, stream>>>(W1, Wih, Whh, W2, wsp);

    dim3 grid(B / 256, NAGENT);
    rnn_main<<<grid, 256, 0, stream>>>(x, hin, b1, bih, bhh, b2, wsp, qout, hout);
}